// Round 3
// baseline (510.321 us; speedup 1.0000x reference)
//
#include <hip/hip_runtime.h>
#include <hip/hip_bf16.h>

// Graph Actor Model — R2: kernel fusion + split-bf16 plane MFMA pipeline.
// Launches: memset(cnt) -> mega(build||encoder||prepack) -> prop -> prop -> head.

#define NN   8192
#define EPAD 128

#define ENC_BLOCKS  256
#define PACK_BLOCKS 8
#define BUILD_BLOCKS 2048
#define MEGA_GRID (ENC_BLOCKS + PACK_BLOCKS + BUILD_BLOCKS)

typedef __attribute__((ext_vector_type(8))) short bf16x8;
typedef __attribute__((ext_vector_type(4))) float f32x4;

// image layout constants (bytes): per-tile = NTILE*160 (hi plane NTILE x 80B, lo plane same)
#define IMG_GCN 0u
#define IMG_GD  327680u
#define IMG_P1  655360u
#define IMG_P2  983040u
#define IMG_PI  1064960u
#define IMG_BYTES 1085440u

// ---------- helpers ----------

__device__ __forceinline__ void split2(float v, unsigned short& h, unsigned short& l) {
    unsigned b = __builtin_bit_cast(unsigned, v);
    unsigned hr = (b + 0x7fffu + ((b >> 16) & 1u)) & 0xffff0000u;
    h = (unsigned short)(hr >> 16);
    float lo = v - __builtin_bit_cast(float, hr);
    unsigned lb = __builtin_bit_cast(unsigned, lo);
    l = (unsigned short)((lb + 0x7fffu + ((lb >> 16) & 1u)) >> 16);
}

__device__ __forceinline__ void splitfrag(const float4& v0, const float4& v1,
                                          bf16x8& ah, bf16x8& al) {
    union { unsigned short us[8]; bf16x8 v; } H, L;
    float vv[8] = {v0.x, v0.y, v0.z, v0.w, v1.x, v1.y, v1.z, v1.w};
    #pragma unroll
    for (int j = 0; j < 8; ++j) {
        unsigned short h, l;
        split2(vv[j], h, l);
        H.us[j] = h; L.us[j] = l;
    }
    ah = H.v; al = L.v;
}

__device__ __forceinline__ void gload_lds16(const void* g, void* l) {
    typedef const __attribute__((address_space(1))) unsigned int GU;
    typedef __attribute__((address_space(3))) unsigned int LU;
    __builtin_amdgcn_global_load_lds((GU*)g, (LU*)l, 16, 0, 0);
}

__device__ __forceinline__ void stageB(const unsigned char* src, unsigned char* lds,
                                       int nchunks, int wave, int lane) {
    for (int i = wave; i < nchunks; i += 8)
        gload_lds16(src + i * 1024 + lane * 16, lds + i * 1024);
}

// ---------- edge build (partition of mega) ----------

__device__ void build_part(const float4* adj4, int* cnt, int* edges, int bid) {
    const size_t total = (size_t)NN * NN / 4;
    const size_t stride = (size_t)BUILD_BLOCKS * 512;
    for (size_t i = (size_t)bid * 512 + threadIdx.x; i < total; i += stride) {
        float4 v = adj4[i];
        if (v.x != 0.f || v.y != 0.f || v.z != 0.f || v.w != 0.f) {
            size_t base = i * 4;
            int r  = (int)(base / NN);
            int c0 = (int)(base % NN);
            float vv[4] = {v.x, v.y, v.z, v.w};
            #pragma unroll
            for (int j = 0; j < 4; ++j) {
                if (vv[j] != 0.f) {
                    int c = c0 + j;
                    int slot = atomicAdd(&cnt[c], 1);
                    if (slot < EPAD) edges[(size_t)c * EPAD + slot] = r;
                }
            }
        }
    }
}

// ---------- pre-pack head weight images (partition of mega) ----------
// tile t of a layer: rows n in [0,NTILE); hi plane n*80 + k*2, lo plane +NTILE*80.
// tile index = nh*(K/32) + ks ; col = nh*128 + n ; k = ks*32 + c*4 + j.

__device__ void pack_layer(const float* W, int NOUT, int K, int NTILE, int ntiles,
                           unsigned imgoff, int rank, int nblk,
                           unsigned char* img) {
    const int nks = K / 32;
    const int total = ntiles * NTILE;
    for (int u = rank * 512 + threadIdx.x; u < total; u += nblk * 512) {
        int tile = u / NTILE;
        int n    = u % NTILE;
        int nh   = tile / nks;
        int ks   = tile % nks;
        int col  = nh * 128 + n;
        unsigned char* tb = img + imgoff + (size_t)tile * NTILE * 160;
        #pragma unroll
        for (int c = 0; c < 8; ++c) {
            unsigned short h[4], l[4];
            #pragma unroll
            for (int j = 0; j < 4; ++j) {
                float w = W[(size_t)(ks * 32 + c * 4 + j) * NOUT + col];
                split2(w, h[j], l[j]);
            }
            uint2 hv, lv;
            hv.x = (unsigned)h[0] | ((unsigned)h[1] << 16);
            hv.y = (unsigned)h[2] | ((unsigned)h[3] << 16);
            lv.x = (unsigned)l[0] | ((unsigned)l[1] << 16);
            lv.y = (unsigned)l[2] | ((unsigned)l[3] << 16);
            *(uint2*)(tb + n * 80 + c * 8) = hv;
            *(uint2*)(tb + NTILE * 80 + n * 80 + c * 8) = lv;
        }
    }
}

// ---------- encoder (partition of mega): X = relu(relu(F@We1+b)@We2+b) ----------

__device__ void enc_stage(const float* W, int NOUT, int col0, int NT, int k0,
                          unsigned char* bufB) {
    for (int u = threadIdx.x; u < NT * 8; u += 512) {
        int n = u >> 3, c = u & 7;
        unsigned short h[4], l[4];
        #pragma unroll
        for (int j = 0; j < 4; ++j) {
            float w = W[(size_t)(k0 + c * 4 + j) * NOUT + col0 + n];
            split2(w, h[j], l[j]);
        }
        uint2 hv, lv;
        hv.x = (unsigned)h[0] | ((unsigned)h[1] << 16);
        hv.y = (unsigned)h[2] | ((unsigned)h[3] << 16);
        lv.x = (unsigned)l[0] | ((unsigned)l[1] << 16);
        lv.y = (unsigned)l[2] | ((unsigned)l[3] << 16);
        *(uint2*)(bufB + n * 80 + c * 8) = hv;
        *(uint2*)(bufB + NT * 80 + n * 80 + c * 8) = lv;
    }
}

__device__ void enc_part(const float* feat,
                         const float* We1, const float* be1,
                         const float* We2, const float* be2,
                         float* Hs, float* X, int bid, unsigned char* bufB) {
    const int t = threadIdx.x, lane = t & 63, wave = t >> 6;
    const int wr = wave >> 2, wc = wave & 3, lm = lane & 15, lk = lane >> 4;
    const int r0 = bid * 32;

    // ---- GEMM1: T1 = relu(F @ We1 + b) -> Hs cols 0..63 (stride 256)
    const float* frow = feat + (size_t)(r0 + wr * 16 + lm) * 64 + lk * 8;
    float4 fa0[2], fa1[2];
    #pragma unroll
    for (int ks = 0; ks < 2; ++ks) {
        fa0[ks] = *(const float4*)(frow + ks * 32);
        fa1[ks] = *(const float4*)(frow + ks * 32 + 4);
    }
    f32x4 acc0 = {0.f,0.f,0.f,0.f}, acc1 = {0.f,0.f,0.f,0.f};
    #pragma unroll
    for (int ks = 0; ks < 2; ++ks) {
        enc_stage(We1, 64, 0, 64, ks * 32, bufB);
        __syncthreads();
        if (wc < 2) {
            bf16x8 ah, al; splitfrag(fa0[ks], fa1[ks], ah, al);
            int n0 = wc * 32 + lm;
            bf16x8 bh0 = *(const bf16x8*)(bufB + n0 * 80 + lk * 16);
            bf16x8 bl0 = *(const bf16x8*)(bufB + 5120 + n0 * 80 + lk * 16);
            bf16x8 bh1 = *(const bf16x8*)(bufB + (n0 + 16) * 80 + lk * 16);
            bf16x8 bl1 = *(const bf16x8*)(bufB + 5120 + (n0 + 16) * 80 + lk * 16);
            acc0 = __builtin_amdgcn_mfma_f32_16x16x32_bf16(ah, bh0, acc0, 0, 0, 0);
            acc0 = __builtin_amdgcn_mfma_f32_16x16x32_bf16(ah, bl0, acc0, 0, 0, 0);
            acc0 = __builtin_amdgcn_mfma_f32_16x16x32_bf16(al, bh0, acc0, 0, 0, 0);
            acc1 = __builtin_amdgcn_mfma_f32_16x16x32_bf16(ah, bh1, acc1, 0, 0, 0);
            acc1 = __builtin_amdgcn_mfma_f32_16x16x32_bf16(ah, bl1, acc1, 0, 0, 0);
            acc1 = __builtin_amdgcn_mfma_f32_16x16x32_bf16(al, bh1, acc1, 0, 0, 0);
        }
        __syncthreads();
    }
    if (wc < 2) {
        #pragma unroll
        for (int fn = 0; fn < 2; ++fn) {
            int col = wc * 32 + fn * 16 + lm;
            float b = be1[col];
            f32x4 a = fn ? acc1 : acc0;
            #pragma unroll
            for (int q = 0; q < 4; ++q) {
                int row = r0 + wr * 16 + lk * 4 + q;
                Hs[(size_t)row * 256 + col] = fmaxf(a[q] + b, 0.f);
            }
        }
    }
    __threadfence();
    __syncthreads();

    // ---- GEMM2: X = relu(T1 @ We2 + b), N=256 in two halves
    const float* hrow = Hs + (size_t)(r0 + wr * 16 + lm) * 256 + lk * 8;
    float4 ha0[2], ha1[2];
    #pragma unroll
    for (int ks = 0; ks < 2; ++ks) {
        ha0[ks] = *(const float4*)(hrow + ks * 32);
        ha1[ks] = *(const float4*)(hrow + ks * 32 + 4);
    }
    #pragma unroll
    for (int nh = 0; nh < 2; ++nh) {
        f32x4 c0 = {0.f,0.f,0.f,0.f}, c1 = {0.f,0.f,0.f,0.f};
        #pragma unroll
        for (int ks = 0; ks < 2; ++ks) {
            enc_stage(We2, 256, nh * 128, 128, ks * 32, bufB);
            __syncthreads();
            bf16x8 ah, al; splitfrag(ha0[ks], ha1[ks], ah, al);
            int n0 = wc * 32 + lm;
            bf16x8 bh0 = *(const bf16x8*)(bufB + n0 * 80 + lk * 16);
            bf16x8 bl0 = *(const bf16x8*)(bufB + 10240 + n0 * 80 + lk * 16);
            bf16x8 bh1 = *(const bf16x8*)(bufB + (n0 + 16) * 80 + lk * 16);
            bf16x8 bl1 = *(const bf16x8*)(bufB + 10240 + (n0 + 16) * 80 + lk * 16);
            c0 = __builtin_amdgcn_mfma_f32_16x16x32_bf16(ah, bh0, c0, 0, 0, 0);
            c0 = __builtin_amdgcn_mfma_f32_16x16x32_bf16(ah, bl0, c0, 0, 0, 0);
            c0 = __builtin_amdgcn_mfma_f32_16x16x32_bf16(al, bh0, c0, 0, 0, 0);
            c1 = __builtin_amdgcn_mfma_f32_16x16x32_bf16(ah, bh1, c1, 0, 0, 0);
            c1 = __builtin_amdgcn_mfma_f32_16x16x32_bf16(ah, bl1, c1, 0, 0, 0);
            c1 = __builtin_amdgcn_mfma_f32_16x16x32_bf16(al, bh1, c1, 0, 0, 0);
            __syncthreads();
        }
        #pragma unroll
        for (int fn = 0; fn < 2; ++fn) {
            int colg = nh * 128 + wc * 32 + fn * 16 + lm;
            float b = be2[colg];
            f32x4 a = fn ? c1 : c0;
            #pragma unroll
            for (int q = 0; q < 4; ++q) {
                int row = r0 + wr * 16 + lk * 4 + q;
                X[(size_t)row * 256 + colg] = fmaxf(a[q] + b, 0.f);
            }
        }
    }
}

// ---------- mega kernel ----------

__global__ __launch_bounds__(512) void mega_kernel(
    const float* feat, const float4* adj4, int* cnt, int* edges,
    const float* We1, const float* be1, const float* We2, const float* be2,
    const float* Wgcn, const float* Wgd, const float* Wp1, const float* Wp2,
    const float* Wpi,
    float* Hs, float* X, unsigned char* img)
{
    __shared__ unsigned char bufB[20480];
    int bid = blockIdx.x;
    if (bid < ENC_BLOCKS) {
        enc_part(feat, We1, be1, We2, be2, Hs, X, bid, bufB);
    } else if (bid < ENC_BLOCKS + PACK_BLOCKS) {
        int pb = bid - ENC_BLOCKS;
        if (pb < 2)      pack_layer(Wgcn, 256, 256, 128, 16, IMG_GCN, pb,     2, img);
        else if (pb < 4) pack_layer(Wgd,  256, 256, 128, 16, IMG_GD,  pb - 2, 2, img);
        else if (pb < 6) pack_layer(Wp1,  128, 512, 128, 16, IMG_P1,  pb - 4, 2, img);
        else if (pb < 7) pack_layer(Wp2,  128, 128, 128,  4, IMG_P2,  0,      1, img);
        else             pack_layer(Wpi,   32, 128,  32,  4, IMG_PI,  0,      1, img);
    } else {
        build_part(adj4, cnt, edges, bid - ENC_BLOCKS - PACK_BLOCKS);
    }
}

// ---------- sparse propagation ----------

__global__ __launch_bounds__(256) void prop_kernel(
    const float* __restrict__ h, const int* __restrict__ cnt,
    const int* __restrict__ edges, float* __restrict__ out)
{
    __shared__ int   se[EPAD];
    __shared__ float sd[EPAD];
    int c = blockIdx.x;
    int t = threadIdx.x;
    int n = cnt[c]; if (n > EPAD) n = EPAD;
    if (t < n) {
        int r = edges[(size_t)c * EPAD + t];
        se[t] = r;
        int dr = cnt[r];
        sd[t] = dr > 0 ? rsqrtf((float)dr) : 0.f;
    }
    __syncthreads();
    float a0 = 0.f, a1 = 0.f, a2 = 0.f, a3 = 0.f;
    int i = 0;
    for (; i + 4 <= n; i += 4) {
        a0 += sd[i + 0] * h[(size_t)se[i + 0] * 256 + t];
        a1 += sd[i + 1] * h[(size_t)se[i + 1] * 256 + t];
        a2 += sd[i + 2] * h[(size_t)se[i + 2] * 256 + t];
        a3 += sd[i + 3] * h[(size_t)se[i + 3] * 256 + t];
    }
    for (; i < n; ++i) a0 += sd[i] * h[(size_t)se[i] * 256 + t];
    int dc = cnt[c];
    float di = dc > 0 ? rsqrtf((float)dc) : 0.f;
    out[(size_t)c * 256 + t] = di * ((a0 + a1) + (a2 + a3));
}

// ---------- fused head: gcn -> gd -> p1(concat X) -> p2 -> pi ----------

template<int NKS, int NNH, int NTILE, bool RELU, bool FINAL>
__device__ __forceinline__ void do_gemm(const float* A, const float* A2, int r0,
        const unsigned char* img, const float* bias, float* D, int dS,
        const float* maskv, unsigned char* bufB) {
    constexpr int TILEB  = NTILE * 160;
    constexpr int CHUNKS = TILEB / 1024;
    constexpr int GROUP  = NKS < 8 ? NKS : 8;
    constexpr int NGRP   = NKS / GROUP;
    const int t = threadIdx.x, lane = t & 63, wave = t >> 6;
    const int wr = wave >> 2, wc = wave & 3, lm = lane & 15, lk = lane >> 4;
    const bool active = (wc * 32) < NTILE;
    const float* arow  = A + (size_t)(r0 + wr * 16 + lm) * 256 + lk * 8;
    const float* arow2 = A2 ? (A2 + (size_t)(r0 + wr * 16 + lm) * 256 + lk * 8) : arow;

    stageB(img, bufB, CHUNKS, wave, lane);
    __syncthreads();
    int cur = 0;
    #pragma unroll
    for (int nh = 0; nh < NNH; ++nh) {
        f32x4 acc0 = {0.f,0.f,0.f,0.f}, acc1 = {0.f,0.f,0.f,0.f};
        #pragma unroll
        for (int g = 0; g < NGRP; ++g) {
            float4 araw0[GROUP], araw1[GROUP];
            if (active) {
                #pragma unroll
                for (int kk = 0; kk < GROUP; ++kk) {
                    int ks = g * GROUP + kk;
                    const float* ap = (NKS == 16 && ks >= 8) ? arow2 : arow;
                    int koff = (NKS == 16 ? (ks & 7) : ks) * 32;
                    araw0[kk] = *(const float4*)(ap + koff);
                    araw1[kk] = *(const float4*)(ap + koff + 4);
                }
            }
            #pragma unroll
            for (int kk = 0; kk < GROUP; ++kk) {
                int ks = g * GROUP + kk;
                int tile = nh * NKS + ks;
                if (tile + 1 < NNH * NKS)
                    stageB(img + (size_t)(tile + 1) * TILEB,
                           bufB + (cur ^ 1) * 20480, CHUNKS, wave, lane);
                if (active) {
                    bf16x8 ah, al; splitfrag(araw0[kk], araw1[kk], ah, al);
                    const unsigned char* bb = bufB + cur * 20480;
                    int n0 = wc * 32 + lm;
                    bf16x8 bh0 = *(const bf16x8*)(bb + n0 * 80 + lk * 16);
                    bf16x8 bl0 = *(const bf16x8*)(bb + NTILE * 80 + n0 * 80 + lk * 16);
                    bf16x8 bh1 = *(const bf16x8*)(bb + (n0 + 16) * 80 + lk * 16);
                    bf16x8 bl1 = *(const bf16x8*)(bb + NTILE * 80 + (n0 + 16) * 80 + lk * 16);
                    acc0 = __builtin_amdgcn_mfma_f32_16x16x32_bf16(ah, bh0, acc0, 0, 0, 0);
                    acc0 = __builtin_amdgcn_mfma_f32_16x16x32_bf16(ah, bl0, acc0, 0, 0, 0);
                    acc0 = __builtin_amdgcn_mfma_f32_16x16x32_bf16(al, bh0, acc0, 0, 0, 0);
                    acc1 = __builtin_amdgcn_mfma_f32_16x16x32_bf16(ah, bh1, acc1, 0, 0, 0);
                    acc1 = __builtin_amdgcn_mfma_f32_16x16x32_bf16(ah, bl1, acc1, 0, 0, 0);
                    acc1 = __builtin_amdgcn_mfma_f32_16x16x32_bf16(al, bh1, acc1, 0, 0, 0);
                }
                __syncthreads();
                cur ^= 1;
            }
        }
        if (active) {
            #pragma unroll
            for (int fn = 0; fn < 2; ++fn) {
                int colg = nh * 128 + wc * 32 + fn * 16 + lm;
                float b = bias[colg];
                f32x4 a = fn ? acc1 : acc0;
                #pragma unroll
                for (int q = 0; q < 4; ++q) {
                    int row = r0 + wr * 16 + lk * 4 + q;
                    float v = a[q] + b;
                    if (RELU) v = fmaxf(v, 0.f);
                    if (FINAL) v *= maskv[row];
                    D[(size_t)row * dS + colg] = v;
                }
            }
        }
    }
    __threadfence();
    __syncthreads();
}

__global__ __launch_bounds__(512) void head_kernel(
    float* Hbuf, float* Tbuf, const float* X, const unsigned char* img,
    const float* bgcn, const float* bgd, const float* bp1,
    const float* bp2,  const float* bpi,
    const float* maskv, float* out)
{
    __shared__ unsigned char bufB[40960];
    int r0 = blockIdx.x * 32;
    // gcn: T = relu(H @ Wgcn + b)
    do_gemm<8, 2, 128, true,  false>(Hbuf, nullptr, r0, img + IMG_GCN, bgcn, Tbuf, 256, nullptr, bufB);
    // gd:  H = relu(T @ Wgd + b)   (H = Xg2)
    do_gemm<8, 2, 128, true,  false>(Tbuf, nullptr, r0, img + IMG_GD,  bgd,  Hbuf, 256, nullptr, bufB);
    // p1:  T[:,0:128] = relu([H|X] @ Wp1 + b)
    do_gemm<16, 1, 128, true, false>(Hbuf, X,       r0, img + IMG_P1,  bp1,  Tbuf, 256, nullptr, bufB);
    // p2:  H[:,0:128] = relu(T @ Wp2 + b)
    do_gemm<4, 1, 128, true,  false>(Tbuf, nullptr, r0, img + IMG_P2,  bp2,  Hbuf, 256, nullptr, bufB);
    // pi:  out = (H @ Wpi + b) * mask
    do_gemm<4, 1, 32, false,  true >(Hbuf, nullptr, r0, img + IMG_PI,  bpi,  out,  32,  maskv,  bufB);
}

// ---------- launch ----------

extern "C" void kernel_launch(void* const* d_in, const int* in_sizes, int n_in,
                              void* d_out, int out_size, void* d_ws, size_t ws_size,
                              hipStream_t stream) {
    const float* features = (const float*)d_in[0];
    const float* adj      = (const float*)d_in[1];
    const float* mask     = (const float*)d_in[2];
    const float* W_e1  = (const float*)d_in[3];
    const float* b_e1  = (const float*)d_in[4];
    const float* W_e2  = (const float*)d_in[5];
    const float* b_e2  = (const float*)d_in[6];
    const float* W_gcn = (const float*)d_in[7];
    const float* b_gcn = (const float*)d_in[8];
    const float* W_gd  = (const float*)d_in[9];
    const float* b_gd  = (const float*)d_in[10];
    const float* W_p1  = (const float*)d_in[11];
    const float* b_p1  = (const float*)d_in[12];
    const float* W_p2  = (const float*)d_in[13];
    const float* b_p2  = (const float*)d_in[14];
    const float* W_pi  = (const float*)d_in[15];
    const float* b_pi  = (const float*)d_in[16];
    float* out = (float*)d_out;

    float* ws = (float*)d_ws;
    float* X  = ws;                                  // [NN,256]
    float* T  = X + (size_t)NN * 256;                // [NN,256]
    float* Hs = T + (size_t)NN * 256;                // [NN,256] enc scratch -> prop2 out
    int* cnt   = (int*)(Hs + (size_t)NN * 256);      // [NN]
    int* edges = cnt + NN;                           // [NN][EPAD]
    unsigned char* img = (unsigned char*)(edges + (size_t)NN * EPAD);  // 1.04 MB

    // cnt = 0 (must precede build atomics)
    hipMemsetAsync(cnt, 0, NN * sizeof(int), stream);

    // build edge list  ||  encoder MLP  ||  pre-pack head weight images
    mega_kernel<<<MEGA_GRID, 512, 0, stream>>>(
        features, (const float4*)adj, cnt, edges,
        W_e1, b_e1, W_e2, b_e2, W_gcn, W_gd, W_p1, W_p2, W_pi,
        Hs, X, img);

    // SGConv K=2
    prop_kernel<<<NN, 256, 0, stream>>>(X, cnt, edges, T);
    prop_kernel<<<NN, 256, 0, stream>>>(T, cnt, edges, Hs);

    // fused dense head
    head_kernel<<<256, 512, 0, stream>>>(
        Hs, T, X, img, b_gcn, b_gd, b_p1, b_p2, b_pi, mask, out);
}

// Round 5
// 195.023 us; speedup vs baseline: 2.6167x; 2.6167x over previous
//
#include <hip/hip_runtime.h>
#include <hip/hip_bf16.h>

// Graph Actor Model — R4 = R3 + fix: gemm3 must offset the weight image by
// blockIdx.y's column tile-set (R3 read nh=0's tiles for ALL column blocks).
//  - weights pre-packed (split-bf16, swizzled) into global images, hidden
//    under the adjacency stream via grid partition
//  - GEMMs: whole-K B-window staged once via global_load_lds; K-loop has
//    ZERO barriers (A read direct from global L2, split in-register)
//  - prop: float2, 2 nodes/block, inline dinv

#define NN   8192
#define EPAD 128
#define BUILD_BLOCKS 4096
#define PACK_BLOCKS  8

typedef __attribute__((ext_vector_type(8))) short bf16x8;
typedef __attribute__((ext_vector_type(4))) float f32x4;

// image byte offsets (all 4KB-aligned); tile = BN*128 bytes
#define IMG_E1  0u
#define IMG_E2  16384u
#define IMG_GCN 81920u
#define IMG_GD  344064u
#define IMG_P1  606208u
#define IMG_P2  868352u
#define IMG_PI  933888u
#define IMG_BYTES 950272u

// ---------- split-bf16 helpers ----------

__device__ __forceinline__ unsigned f32_to_split(float v) {
    unsigned b = __builtin_bit_cast(unsigned, v);
    unsigned hi = (b + 0x7fffu + ((b >> 16) & 1u)) & 0xffff0000u;
    float lo = v - __builtin_bit_cast(float, hi);
    unsigned lb = __builtin_bit_cast(unsigned, lo);
    unsigned lo16 = (lb + 0x7fffu + ((lb >> 16) & 1u)) >> 16;
    return hi | lo16;
}

// q0 = packed k..k+3, q1 = packed k+4..k+7 -> hi frag, lo frag
__device__ __forceinline__ void unpack_frags(const uint4& q0, const uint4& q1,
                                             bf16x8& hi, bf16x8& lo) {
    union { unsigned u[4]; bf16x8 v; } H, L;
    H.u[0] = (q0.y & 0xffff0000u) | (q0.x >> 16);
    H.u[1] = (q0.w & 0xffff0000u) | (q0.z >> 16);
    H.u[2] = (q1.y & 0xffff0000u) | (q1.x >> 16);
    H.u[3] = (q1.w & 0xffff0000u) | (q1.z >> 16);
    L.u[0] = (q0.y << 16) | (q0.x & 0xffffu);
    L.u[1] = (q0.w << 16) | (q0.z & 0xffffu);
    L.u[2] = (q1.y << 16) | (q1.x & 0xffffu);
    L.u[3] = (q1.w << 16) | (q1.z & 0xffffu);
    hi = H.v; lo = L.v;
}

__device__ __forceinline__ void split2(float v, unsigned short& h, unsigned short& l) {
    unsigned b = __builtin_bit_cast(unsigned, v);
    unsigned hr = (b + 0x7fffu + ((b >> 16) & 1u)) & 0xffff0000u;
    h = (unsigned short)(hr >> 16);
    float lo = v - __builtin_bit_cast(float, hr);
    unsigned lb = __builtin_bit_cast(unsigned, lo);
    l = (unsigned short)((lb + 0x7fffu + ((lb >> 16) & 1u)) >> 16);
}

__device__ __forceinline__ void splitfrag(const float4& v0, const float4& v1,
                                          bf16x8& ah, bf16x8& al) {
    union { unsigned short us[8]; bf16x8 v; } H, L;
    float vv[8] = {v0.x, v0.y, v0.z, v0.w, v1.x, v1.y, v1.z, v1.w};
    #pragma unroll
    for (int j = 0; j < 8; ++j) {
        unsigned short h, l;
        split2(vv[j], h, l);
        H.us[j] = h; L.us[j] = l;
    }
    ah = H.v; al = L.v;
}

__device__ __forceinline__ void gload_lds16(const void* g, void* l) {
    typedef const __attribute__((address_space(1))) unsigned int GU;
    typedef __attribute__((address_space(3))) unsigned int LU;
    __builtin_amdgcn_global_load_lds((GU*)g, (LU*)l, 16, 0, 0);
}

// ---------- build (edge list) + pack (weight images), grid-partitioned ----------

__device__ void build_part(const float4* adj4, int* cnt, int* edges, int bid) {
    const size_t total = (size_t)NN * NN / 4;
    const size_t stride = (size_t)BUILD_BLOCKS * 256;
    for (size_t i = (size_t)bid * 256 + threadIdx.x; i < total; i += stride) {
        float4 v = adj4[i];
        if (v.x != 0.f || v.y != 0.f || v.z != 0.f || v.w != 0.f) {
            size_t base = i * 4;
            int r  = (int)(base / NN);
            int c0 = (int)(base % NN);
            float vv[4] = {v.x, v.y, v.z, v.w};
            #pragma unroll
            for (int j = 0; j < 4; ++j) {
                if (vv[j] != 0.f) {
                    int c = c0 + j;
                    int slot = atomicAdd(&cnt[c], 1);
                    if (slot < EPAD) edges[(size_t)c * EPAD + slot] = r;
                }
            }
        }
    }
}

// image tile layout == LDS layout the GEMM reads: tile (nh,ks) holds cols
// n in [0,BN), bytes n*128 + ((c ^ (n&7))<<4) = packed u32 quad for k-chunk c.
// tile index = nh*nks + ks  (nh = column block of BN cols).
__device__ void pack_layer(const float* W, int NOUT, int K, int BN_,
                           unsigned imgoff, int rank, int nblk,
                           unsigned char* img) {
    const int nks = K / 32;
    const int total = (NOUT / BN_) * nks * BN_ * 8;   // chunks
    const int tileb = BN_ * 128;
    for (int u = rank * 256 + threadIdx.x; u < total; u += nblk * 256) {
        int tile = u / (BN_ * 8);
        int rem  = u - tile * (BN_ * 8);
        int n    = rem >> 3;
        int c    = rem & 7;
        int nh   = tile / nks;
        int ks   = tile - nh * nks;
        int col  = nh * BN_ + n;
        int kb   = ks * 32 + c * 4;
        uint4 q;
        q.x = f32_to_split(W[(size_t)(kb + 0) * NOUT + col]);
        q.y = f32_to_split(W[(size_t)(kb + 1) * NOUT + col]);
        q.z = f32_to_split(W[(size_t)(kb + 2) * NOUT + col]);
        q.w = f32_to_split(W[(size_t)(kb + 3) * NOUT + col]);
        *(uint4*)(img + imgoff + (size_t)tile * tileb + n * 128 + ((c ^ (n & 7)) << 4)) = q;
    }
}

__global__ __launch_bounds__(256) void buildpack_kernel(
    const float4* adj4, int* cnt, int* edges,
    const float* We1, const float* We2, const float* Wgcn, const float* Wgd,
    const float* Wp1, const float* Wp2, const float* Wpi, unsigned char* img)
{
    int bid = blockIdx.x;
    if (bid < BUILD_BLOCKS) {
        build_part(adj4, cnt, edges, bid);
    } else {
        int pb = bid - BUILD_BLOCKS;
        if (pb < 2)      pack_layer(Wgcn, 256, 256, 64, IMG_GCN, pb,     2, img);
        else if (pb < 4) pack_layer(Wgd,  256, 256, 64, IMG_GD,  pb - 2, 2, img);
        else if (pb < 6) pack_layer(Wp1,  128, 512, 64, IMG_P1,  pb - 4, 2, img);
        else if (pb < 7) { pack_layer(We2, 256,  64, 64, IMG_E2, 0, 1, img);
                           pack_layer(Wp2, 128, 128, 64, IMG_P2, 0, 1, img); }
        else             { pack_layer(We1,  64,  64, 64, IMG_E1, 0, 1, img);
                           pack_layer(Wpi,  32, 128, 32, IMG_PI, 0, 1, img); }
    }
}

// ---------- sparse propagation: 2 nodes/block, float2/thread ----------

__global__ __launch_bounds__(256) void prop_kernel(
    const float* __restrict__ h, const int* __restrict__ cnt,
    const int* __restrict__ edges, float* __restrict__ out)
{
    __shared__ int   se[2][EPAD];
    __shared__ float sd[2][EPAD];
    const int half = threadIdx.x >> 7;
    const int tl   = threadIdx.x & 127;
    const int c = blockIdx.x * 2 + half;
    int n = cnt[c]; if (n > EPAD) n = EPAD;
    if (tl < n) {
        int r = edges[(size_t)c * EPAD + tl];
        se[half][tl] = r;
        int dr = cnt[r];
        sd[half][tl] = dr > 0 ? rsqrtf((float)dr) : 0.f;
    }
    __syncthreads();
    float2 a0{0.f,0.f}, a1{0.f,0.f}, a2{0.f,0.f}, a3{0.f,0.f};
    int i = 0;
    for (; i + 4 <= n; i += 4) {
        float2 v0 = *(const float2*)&h[(size_t)se[half][i+0] * 256 + tl * 2];
        float2 v1 = *(const float2*)&h[(size_t)se[half][i+1] * 256 + tl * 2];
        float2 v2 = *(const float2*)&h[(size_t)se[half][i+2] * 256 + tl * 2];
        float2 v3 = *(const float2*)&h[(size_t)se[half][i+3] * 256 + tl * 2];
        a0.x += sd[half][i+0] * v0.x; a0.y += sd[half][i+0] * v0.y;
        a1.x += sd[half][i+1] * v1.x; a1.y += sd[half][i+1] * v1.y;
        a2.x += sd[half][i+2] * v2.x; a2.y += sd[half][i+2] * v2.y;
        a3.x += sd[half][i+3] * v3.x; a3.y += sd[half][i+3] * v3.y;
    }
    for (; i < n; ++i) {
        float2 v = *(const float2*)&h[(size_t)se[half][i] * 256 + tl * 2];
        a0.x += sd[half][i] * v.x; a0.y += sd[half][i] * v.y;
    }
    int dc = cnt[c];
    float di = dc > 0 ? rsqrtf((float)dc) : 0.f;
    float2 r2;
    r2.x = di * ((a0.x + a1.x) + (a2.x + a3.x));
    r2.y = di * ((a0.y + a1.y) + (a2.y + a3.y));
    *(float2*)&out[(size_t)c * 256 + tl * 2] = r2;
}

// ---------- barrier-free-K MFMA GEMM ----------
// C[r,c] = act(sum_k A[r,k]*W[k,c] + bias[c]) (* mask[r]).
// B (weights) staged from pre-packed image in windows of <=8 k-tiles (64KB);
// inside a window the K-loop has no barriers: A frags read direct from
// global (L2-hot) and split in-register; B frags from LDS.

template<int K1, int K2, int NOUT, int BN, bool RELU, bool MASK>
__global__ __launch_bounds__(256) void gemm3(
    const float* __restrict__ A1, const float* __restrict__ A2,
    const unsigned char* __restrict__ img, const float* __restrict__ bias,
    float* __restrict__ C, const float* __restrict__ maskv)
{
    constexpr int K      = K1 + K2;
    constexpr int NKS    = K / 32;
    constexpr int TILEB  = BN * 128;
    constexpr int WTILES = NKS > 8 ? 8 : NKS;
    constexpr int NWIN   = NKS / WTILES;
    constexpr int WN     = BN / 2;
    constexpr int FN     = WN / 16;          // 2 (BN=64) or 1 (BN=32)
    constexpr int NCHUNK = WTILES * TILEB / 1024;

    __shared__ unsigned char Bs[WTILES * TILEB];

    const int t    = threadIdx.x;
    const int lane = t & 63;
    const int wave = t >> 6;
    const int wr   = wave >> 1;              // 2x2 wave grid
    const int wc   = wave & 1;
    const int lm   = lane & 15;
    const int lk   = lane >> 4;
    const int row0 = blockIdx.x * 64;
    const int col0 = blockIdx.y * BN;
    // R4 FIX: this block's column tile-set within the layer image
    const unsigned char* imgp = img + (size_t)blockIdx.y * NKS * TILEB;

    f32x4 acc[2][FN];
    #pragma unroll
    for (int i = 0; i < 2; ++i)
        #pragma unroll
        for (int j = 0; j < FN; ++j) {
            acc[i][j][0] = 0.f; acc[i][j][1] = 0.f;
            acc[i][j][2] = 0.f; acc[i][j][3] = 0.f;
        }

    #pragma unroll
    for (int w = 0; w < NWIN; ++w) {
        if (w > 0) __syncthreads();          // protect Bs reuse
        #pragma unroll
        for (int i = wave; i < NCHUNK; i += 4)
            gload_lds16(imgp + (size_t)w * WTILES * TILEB + (size_t)i * 1024 + lane * 16,
                        Bs + (size_t)i * 1024);
        __syncthreads();

        #pragma unroll
        for (int kl = 0; kl < WTILES; ++kl) {
            const int ks = w * WTILES + kl;
            const int kg = ks * 32 + lk * 8;
            // B fragments (LDS)
            bf16x8 bh[FN], bl[FN];
            #pragma unroll
            for (int fn = 0; fn < FN; ++fn) {
                int n = wc * WN + fn * 16 + lm;
                const unsigned char* bb = Bs + kl * TILEB + n * 128;
                uint4 q0 = *(const uint4*)(bb + (((lk * 2 + 0) ^ (n & 7)) << 4));
                uint4 q1 = *(const uint4*)(bb + (((lk * 2 + 1) ^ (n & 7)) << 4));
                unpack_frags(q0, q1, bh[fn], bl[fn]);
            }
            // A fragments (global, L2-hot) + MFMA
            #pragma unroll
            for (int fm = 0; fm < 2; ++fm) {
                int m = row0 + wr * 32 + fm * 16 + lm;
                const float* ap; int kk = kg;
                if constexpr (K2 > 0) {
                    if (kg < K1) { ap = A1 + (size_t)m * K1; }
                    else         { ap = A2 + (size_t)m * K2; kk = kg - K1; }
                } else {
                    ap = A1 + (size_t)m * K1;
                }
                float4 v0 = *(const float4*)(ap + kk);
                float4 v1 = *(const float4*)(ap + kk + 4);
                bf16x8 ah, al;
                splitfrag(v0, v1, ah, al);
                #pragma unroll
                for (int fn = 0; fn < FN; ++fn) {
                    acc[fm][fn] = __builtin_amdgcn_mfma_f32_16x16x32_bf16(ah, bh[fn], acc[fm][fn], 0, 0, 0);
                    acc[fm][fn] = __builtin_amdgcn_mfma_f32_16x16x32_bf16(ah, bl[fn], acc[fm][fn], 0, 0, 0);
                    acc[fm][fn] = __builtin_amdgcn_mfma_f32_16x16x32_bf16(al, bh[fn], acc[fm][fn], 0, 0, 0);
                }
            }
        }
    }

    // epilogue: D col = lane&15, row = (lane>>4)*4 + reg
    #pragma unroll
    for (int fm = 0; fm < 2; ++fm) {
        #pragma unroll
        for (int fn = 0; fn < FN; ++fn) {
            int col = col0 + wc * WN + fn * 16 + lm;
            float b = bias[col];
            #pragma unroll
            for (int q = 0; q < 4; ++q) {
                int row = row0 + wr * 32 + fm * 16 + lk * 4 + q;
                float v = acc[fm][fn][q] + b;
                if (RELU) v = fmaxf(v, 0.f);
                if (MASK) v *= maskv[row];
                C[(size_t)row * NOUT + col] = v;
            }
        }
    }
}

// ---------- launch ----------

extern "C" void kernel_launch(void* const* d_in, const int* in_sizes, int n_in,
                              void* d_out, int out_size, void* d_ws, size_t ws_size,
                              hipStream_t stream) {
    const float* features = (const float*)d_in[0];
    const float* adj      = (const float*)d_in[1];
    const float* mask     = (const float*)d_in[2];
    const float* W_e1  = (const float*)d_in[3];
    const float* b_e1  = (const float*)d_in[4];
    const float* W_e2  = (const float*)d_in[5];
    const float* b_e2  = (const float*)d_in[6];
    const float* W_gcn = (const float*)d_in[7];
    const float* b_gcn = (const float*)d_in[8];
    const float* W_gd  = (const float*)d_in[9];
    const float* b_gd  = (const float*)d_in[10];
    const float* W_p1  = (const float*)d_in[11];
    const float* b_p1  = (const float*)d_in[12];
    const float* W_p2  = (const float*)d_in[13];
    const float* b_p2  = (const float*)d_in[14];
    const float* W_pi  = (const float*)d_in[15];
    const float* b_pi  = (const float*)d_in[16];
    float* out = (float*)d_out;

    float* ws = (float*)d_ws;
    float* X  = ws;                                  // [NN,256]
    float* T  = X + (size_t)NN * 256;                // [NN,256] (also holds P1 [NN,128])
    float* Hs = T + (size_t)NN * 256;                // [NN,256] (also holds P2 [NN,128])
    int* cnt   = (int*)(Hs + (size_t)NN * 256);      // [NN]
    int* edges = cnt + NN;                           // [NN][EPAD]
    unsigned char* img = (unsigned char*)(edges + (size_t)NN * EPAD);

    hipMemsetAsync(cnt, 0, NN * sizeof(int), stream);

    // edge list (HBM floor) || weight-image packing (hidden)
    buildpack_kernel<<<BUILD_BLOCKS + PACK_BLOCKS, 256, 0, stream>>>(
        (const float4*)adj, cnt, edges,
        W_e1, W_e2, W_gcn, W_gd, W_p1, W_p2, W_pi, img);

    // encoder: T = relu(F@We1+b), X = relu(T@We2+b)
    gemm3<64, 0, 64, 64, true, false>
        <<<dim3(NN / 64, 1), 256, 0, stream>>>(features, nullptr, img + IMG_E1, b_e1, T, nullptr);
    gemm3<64, 0, 256, 64, true, false>
        <<<dim3(NN / 64, 4), 256, 0, stream>>>(T, nullptr, img + IMG_E2, b_e2, X, nullptr);

    // SGConv K=2
    prop_kernel<<<NN / 2, 256, 0, stream>>>(X, cnt, edges, T);
    prop_kernel<<<NN / 2, 256, 0, stream>>>(T, cnt, edges, Hs);

    // Xg = relu(H@Wgcn+b) -> T ; Xg = relu(T@Wgd+b) -> Hs
    gemm3<256, 0, 256, 64, true, false>
        <<<dim3(NN / 64, 4), 256, 0, stream>>>(Hs, nullptr, img + IMG_GCN, b_gcn, T, nullptr);
    gemm3<256, 0, 256, 64, true, false>
        <<<dim3(NN / 64, 4), 256, 0, stream>>>(T, nullptr, img + IMG_GD, b_gd, Hs, nullptr);

    // P1 = relu([Xg|X]@Wp1+b) -> T ; P2 = relu(P1@Wp2+b) -> Hs
    gemm3<256, 256, 128, 64, true, false>
        <<<dim3(NN / 64, 2), 256, 0, stream>>>(Hs, X, img + IMG_P1, b_p1, T, nullptr);
    gemm3<128, 0, 128, 64, true, false>
        <<<dim3(NN / 64, 2), 256, 0, stream>>>(T, nullptr, img + IMG_P2, b_p2, Hs, nullptr);

    // pi = (P2@Wpi+b)*mask -> out
    gemm3<128, 0, 32, 32, false, true>
        <<<dim3(NN / 64, 1), 256, 0, stream>>>(Hs, nullptr, img + IMG_PI, b_pi, out, mask);
}